// Round 1
// baseline (1230.509 us; speedup 1.0000x reference)
//
#include <hip/hip_runtime.h>

#define TPB 256

// GCN collapses: layer1 aggregation is scalar (in-dim=1), layer2 is float2.
// s[n] = dinv[n]*(t1[n] + xd[n]),  xd = x*dinv,  t1 = scatter(xd[src] -> dst)
// g[n][k] = sum_j relu(s*W1[j]+b1[j]) * W2[j][k];  gd = g*dinv
// o[n][k] = dinv[n]*(t2[n][k] + gd[n][k]) + b2[k]; t2 = scatter(gd[src] -> dst)
// out = log_softmax(o)

__global__ void k_init(float* __restrict__ t1, int* __restrict__ deg,
                       float* __restrict__ t2, int N) {
  int i = blockIdx.x * blockDim.x + threadIdx.x;
  if (i < N) {
    t1[i] = 0.f;
    deg[i] = 1;            // self-loop
    t2[2 * i] = 0.f;
    t2[2 * i + 1] = 0.f;
  }
}

__global__ void k_deg(const int* __restrict__ dst, int E, int* __restrict__ deg) {
  int base = (blockIdx.x * blockDim.x + threadIdx.x) * 4;
  if (base + 4 <= E) {
    int4 d = *reinterpret_cast<const int4*>(dst + base);
    atomicAdd(&deg[d.x], 1);
    atomicAdd(&deg[d.y], 1);
    atomicAdd(&deg[d.z], 1);
    atomicAdd(&deg[d.w], 1);
  } else {
    for (int e = base; e < E; ++e) atomicAdd(&deg[dst[e]], 1);
  }
}

__global__ void k_dinv(const int* __restrict__ deg, const float* __restrict__ x,
                       float* __restrict__ dinv, float* __restrict__ xd, int N) {
  int i = blockIdx.x * blockDim.x + threadIdx.x;
  if (i < N) {
    float di = rsqrtf((float)deg[i]);   // deg >= 1 always (self-loop)
    dinv[i] = di;
    xd[i] = x[i] * di;
  }
}

__global__ void k_pass1(const int* __restrict__ src, const int* __restrict__ dst,
                        const float* __restrict__ xd, float* __restrict__ t1, int E) {
  int base = (blockIdx.x * blockDim.x + threadIdx.x) * 4;
  if (base + 4 <= E) {
    int4 s = *reinterpret_cast<const int4*>(src + base);
    int4 d = *reinterpret_cast<const int4*>(dst + base);
    atomicAdd(&t1[d.x], xd[s.x]);
    atomicAdd(&t1[d.y], xd[s.y]);
    atomicAdd(&t1[d.z], xd[s.z]);
    atomicAdd(&t1[d.w], xd[s.w]);
  } else {
    for (int e = base; e < E; ++e) atomicAdd(&t1[dst[e]], xd[src[e]]);
  }
}

__global__ void k_node(const float* __restrict__ t1, const float* __restrict__ xd,
                       const float* __restrict__ dinv,
                       const float* __restrict__ W1, const float* __restrict__ b1,
                       const float* __restrict__ W2,
                       float* __restrict__ gd, int N) {
  int i = blockIdx.x * blockDim.x + threadIdx.x;
  if (i < N) {
    float di = dinv[i];
    float s = di * (t1[i] + xd[i]);
    float g0 = 0.f, g1 = 0.f;
#pragma unroll
    for (int j = 0; j < 16; ++j) {
      float h = fmaxf(fmaf(s, W1[j], b1[j]), 0.f);
      g0 = fmaf(h, W2[2 * j], g0);
      g1 = fmaf(h, W2[2 * j + 1], g1);
    }
    gd[2 * i] = g0 * di;
    gd[2 * i + 1] = g1 * di;
  }
}

__global__ void k_pass2(const int* __restrict__ src, const int* __restrict__ dst,
                        const float* __restrict__ gd, float* __restrict__ t2, int E) {
  int base = (blockIdx.x * blockDim.x + threadIdx.x) * 4;
  if (base + 4 <= E) {
    int4 s = *reinterpret_cast<const int4*>(src + base);
    int4 d = *reinterpret_cast<const int4*>(dst + base);
    float2 ga = *reinterpret_cast<const float2*>(gd + 2 * s.x);
    float2 gb = *reinterpret_cast<const float2*>(gd + 2 * s.y);
    float2 gc = *reinterpret_cast<const float2*>(gd + 2 * s.z);
    float2 ge = *reinterpret_cast<const float2*>(gd + 2 * s.w);
    atomicAdd(&t2[2 * d.x],     ga.x);
    atomicAdd(&t2[2 * d.x + 1], ga.y);
    atomicAdd(&t2[2 * d.y],     gb.x);
    atomicAdd(&t2[2 * d.y + 1], gb.y);
    atomicAdd(&t2[2 * d.z],     gc.x);
    atomicAdd(&t2[2 * d.z + 1], gc.y);
    atomicAdd(&t2[2 * d.w],     ge.x);
    atomicAdd(&t2[2 * d.w + 1], ge.y);
  } else {
    for (int e = base; e < E; ++e) {
      int s = src[e], d = dst[e];
      atomicAdd(&t2[2 * d],     gd[2 * s]);
      atomicAdd(&t2[2 * d + 1], gd[2 * s + 1]);
    }
  }
}

__global__ void k_final(const float* __restrict__ t2, const float* __restrict__ gd,
                        const float* __restrict__ dinv, const float* __restrict__ b2,
                        float* __restrict__ out, int N) {
  int i = blockIdx.x * blockDim.x + threadIdx.x;
  if (i < N) {
    float di = dinv[i];
    float o0 = di * (t2[2 * i]     + gd[2 * i])     + b2[0];
    float o1 = di * (t2[2 * i + 1] + gd[2 * i + 1]) + b2[1];
    float m = fmaxf(o0, o1);
    float l = m + logf(expf(o0 - m) + expf(o1 - m));
    out[2 * i]     = o0 - l;
    out[2 * i + 1] = o1 - l;
  }
}

extern "C" void kernel_launch(void* const* d_in, const int* in_sizes, int n_in,
                              void* d_out, int out_size, void* d_ws, size_t ws_size,
                              hipStream_t stream) {
  const float* x  = (const float*)d_in[0];
  const int*   ei = (const int*)d_in[1];
  const float* W1 = (const float*)d_in[2];
  const float* b1 = (const float*)d_in[3];
  const float* W2 = (const float*)d_in[4];
  const float* b2 = (const float*)d_in[5];

  const int N = in_sizes[0];      // x is [N,1]
  const int E = in_sizes[1] / 2;  // edge_index is [2,E]
  const int* src = ei;
  const int* dst = ei + E;

  char* ws = (char*)d_ws;
  float* dinv = (float*)ws; ws += (size_t)N * 4;
  float* xd   = (float*)ws; ws += (size_t)N * 4;
  float* t1   = (float*)ws; ws += (size_t)N * 4;
  int*   deg  = (int*)ws;   ws += (size_t)N * 4;
  float* gd   = (float*)ws; ws += (size_t)N * 8;
  float* t2   = (float*)ws; ws += (size_t)N * 8;

  float* out = (float*)d_out;

  int nb_node = (N + TPB - 1) / TPB;
  int nb_edge = ((E + 3) / 4 + TPB - 1) / TPB;

  k_init <<<nb_node, TPB, 0, stream>>>(t1, deg, t2, N);
  k_deg  <<<nb_edge, TPB, 0, stream>>>(dst, E, deg);
  k_dinv <<<nb_node, TPB, 0, stream>>>(deg, x, dinv, xd, N);
  k_pass1<<<nb_edge, TPB, 0, stream>>>(src, dst, xd, t1, E);
  k_node <<<nb_node, TPB, 0, stream>>>(t1, xd, dinv, W1, b1, W2, gd, N);
  k_pass2<<<nb_edge, TPB, 0, stream>>>(src, dst, gd, t2, E);
  k_final<<<nb_node, TPB, 0, stream>>>(t2, gd, dinv, b2, out, N);
}

// Round 2
// 274.782 us; speedup vs baseline: 4.4781x; 4.4781x over previous
//
#include <hip/hip_runtime.h>

#define TPB 256
#define LOG_NPB 9
#define NPB 512            // nodes per bucket (power of two: bucket = dst >> 9)
#define SPLIT 8            // blocks per bucket in accumulation passes
#define CHUNK 8192         // edges per bucketing block
#define KMAX 256           // max buckets supported (N=100000 -> K=196)

// GCN collapse (in-dim=1, out-dim=2):
//   deg[n] = 1 + #incoming edges; dinv = deg^-1/2; xd = x*dinv
//   t1[n] = sum_{e:dst=n} xd[src];  s = dinv*(t1+xd)
//   g[n][k] = sum_j relu(s*W1[j]+b1[j])*W2[j][k];  gd = g*dinv
//   t2[n][k] = sum_{e:dst=n} gd[src][k]
//   o[n][k] = dinv*(t2+gd) + b2;  out = log_softmax(o)
// All scatters are bucketed by dst into K buckets of 512 nodes -> LDS bins,
// no global atomics on the hot path.

__global__ void k_reset(int* __restrict__ gcur, int K) {
  int i = blockIdx.x * blockDim.x + threadIdx.x;
  if (i < K) gcur[i] = 0;
}

__global__ void k_bucket(const int* __restrict__ src, const int* __restrict__ dst,
                         int E, int K, int cap,
                         int* __restrict__ gcur,
                         int* __restrict__ src_b, unsigned short* __restrict__ ldst_b) {
  __shared__ int hist[KMAX];
  __shared__ int cur[KMAX];
  int e0 = blockIdx.x * CHUNK;
  int e1 = min(e0 + CHUNK, E);
  for (int b = threadIdx.x; b < K; b += TPB) hist[b] = 0;
  __syncthreads();
  for (int e = e0 + threadIdx.x; e < e1; e += TPB)
    atomicAdd(&hist[dst[e] >> LOG_NPB], 1);
  __syncthreads();
  for (int b = threadIdx.x; b < K; b += TPB)
    cur[b] = atomicAdd(&gcur[b], hist[b]);   // global reservation (few per block)
  __syncthreads();
  for (int e = e0 + threadIdx.x; e < e1; e += TPB) {
    int d = dst[e];
    int b = d >> LOG_NPB;
    int p = atomicAdd(&cur[b], 1);           // LDS cursor -> global position
    if (p < cap) {
      src_b[b * cap + p] = src[e];
      ldst_b[b * cap + p] = (unsigned short)(d & (NPB - 1));
    }
  }
}

__global__ void k_deg(const unsigned short* __restrict__ ldst_b,
                      const int* __restrict__ gcur, int cap,
                      int* __restrict__ pdeg, int Npad) {
  int b = blockIdx.x / SPLIT, s = blockIdx.x % SPLIT;
  __shared__ int bins[NPB];
  for (int i = threadIdx.x; i < NPB; i += TPB) bins[i] = 0;
  __syncthreads();
  int cnt = min(gcur[b], cap);
  int lo = b * cap + (int)(((long long)cnt * s) / SPLIT);
  int hi = b * cap + (int)(((long long)cnt * (s + 1)) / SPLIT);
  for (int e = lo + threadIdx.x; e < hi; e += TPB)
    atomicAdd(&bins[ldst_b[e]], 1);
  __syncthreads();
  int base = b << LOG_NPB;
  for (int i = threadIdx.x; i < NPB; i += TPB)
    pdeg[s * Npad + base + i] = bins[i];
}

__global__ void k_dinv(const int* __restrict__ pdeg, const float* __restrict__ x,
                       float* __restrict__ dinv, float* __restrict__ xd,
                       int N, int Npad) {
  int i = blockIdx.x * TPB + threadIdx.x;
  if (i >= N) return;
  int d = 1;  // self-loop
#pragma unroll
  for (int s = 0; s < SPLIT; ++s) d += pdeg[s * Npad + i];
  float di = rsqrtf((float)d);
  dinv[i] = di;
  xd[i] = x[i] * di;
}

__global__ void k_pass1(const int* __restrict__ src_b, const unsigned short* __restrict__ ldst_b,
                        const int* __restrict__ gcur, int cap,
                        const float* __restrict__ xd,
                        float* __restrict__ pt1, int Npad) {
  int b = blockIdx.x / SPLIT, s = blockIdx.x % SPLIT;
  __shared__ float bins[NPB];
  for (int i = threadIdx.x; i < NPB; i += TPB) bins[i] = 0.f;
  __syncthreads();
  int cnt = min(gcur[b], cap);
  int lo = b * cap + (int)(((long long)cnt * s) / SPLIT);
  int hi = b * cap + (int)(((long long)cnt * (s + 1)) / SPLIT);
  for (int e = lo + threadIdx.x; e < hi; e += TPB)
    atomicAdd(&bins[ldst_b[e]], xd[src_b[e]]);
  __syncthreads();
  int base = b << LOG_NPB;
  for (int i = threadIdx.x; i < NPB; i += TPB)
    pt1[s * Npad + base + i] = bins[i];
}

__global__ void k_node(const float* __restrict__ pt1, const float* __restrict__ xd,
                       const float* __restrict__ dinv,
                       const float* __restrict__ W1, const float* __restrict__ b1,
                       const float* __restrict__ W2,
                       float* __restrict__ gd, int N, int Npad) {
  int i = blockIdx.x * TPB + threadIdx.x;
  if (i >= N) return;
  float t = 0.f;
#pragma unroll
  for (int s = 0; s < SPLIT; ++s) t += pt1[s * Npad + i];
  float di = dinv[i];
  float sv = di * (t + xd[i]);
  float g0 = 0.f, g1 = 0.f;
#pragma unroll
  for (int j = 0; j < 16; ++j) {
    float h = fmaxf(fmaf(sv, W1[j], b1[j]), 0.f);
    g0 = fmaf(h, W2[2 * j], g0);
    g1 = fmaf(h, W2[2 * j + 1], g1);
  }
  float2 o;
  o.x = g0 * di;
  o.y = g1 * di;
  *reinterpret_cast<float2*>(gd + 2 * i) = o;
}

__global__ void k_pass2(const int* __restrict__ src_b, const unsigned short* __restrict__ ldst_b,
                        const int* __restrict__ gcur, int cap,
                        const float* __restrict__ gd,
                        float* __restrict__ pt2, int Npad) {
  int b = blockIdx.x / SPLIT, s = blockIdx.x % SPLIT;
  __shared__ float binx[NPB];
  __shared__ float biny[NPB];
  for (int i = threadIdx.x; i < NPB; i += TPB) { binx[i] = 0.f; biny[i] = 0.f; }
  __syncthreads();
  int cnt = min(gcur[b], cap);
  int lo = b * cap + (int)(((long long)cnt * s) / SPLIT);
  int hi = b * cap + (int)(((long long)cnt * (s + 1)) / SPLIT);
  for (int e = lo + threadIdx.x; e < hi; e += TPB) {
    int sn = src_b[e];
    float2 g = *reinterpret_cast<const float2*>(gd + 2 * sn);
    int l = ldst_b[e];
    atomicAdd(&binx[l], g.x);
    atomicAdd(&biny[l], g.y);
  }
  __syncthreads();
  int base = b << LOG_NPB;
  for (int i = threadIdx.x; i < NPB; i += TPB) {
    float2 o;
    o.x = binx[i];
    o.y = biny[i];
    *reinterpret_cast<float2*>(pt2 + (size_t)s * 2 * Npad + 2 * (base + i)) = o;
  }
}

__global__ void k_final(const float* __restrict__ pt2, const float* __restrict__ gd,
                        const float* __restrict__ dinv, const float* __restrict__ b2,
                        float* __restrict__ out, int N, int Npad) {
  int i = blockIdx.x * TPB + threadIdx.x;
  if (i >= N) return;
  float t0 = 0.f, t1 = 0.f;
#pragma unroll
  for (int s = 0; s < SPLIT; ++s) {
    float2 p = *reinterpret_cast<const float2*>(pt2 + (size_t)s * 2 * Npad + 2 * i);
    t0 += p.x;
    t1 += p.y;
  }
  float di = dinv[i];
  float o0 = di * (t0 + gd[2 * i]) + b2[0];
  float o1 = di * (t1 + gd[2 * i + 1]) + b2[1];
  float m = fmaxf(o0, o1);
  float l = m + logf(expf(o0 - m) + expf(o1 - m));
  out[2 * i] = o0 - l;
  out[2 * i + 1] = o1 - l;
}

extern "C" void kernel_launch(void* const* d_in, const int* in_sizes, int n_in,
                              void* d_out, int out_size, void* d_ws, size_t ws_size,
                              hipStream_t stream) {
  const float* x  = (const float*)d_in[0];
  const int*   ei = (const int*)d_in[1];
  const float* W1 = (const float*)d_in[2];
  const float* b1 = (const float*)d_in[3];
  const float* W2 = (const float*)d_in[4];
  const float* b2 = (const float*)d_in[5];

  const int N = in_sizes[0];      // x is [N,1]
  const int E = in_sizes[1] / 2;  // edge_index is [2,E]
  const int* src = ei;
  const int* dst = ei + E;

  const int K = (N + NPB - 1) >> LOG_NPB;   // 196 buckets
  const int Npad = K << LOG_NPB;            // 100352
  int mean = (int)(((long long)E * NPB) / N);
  int cap = mean + mean / 16 + 512;         // generous slack over binomial std
  cap = (cap + 3) & ~3;

  char* ws = (char*)d_ws;
  auto align256 = [&](size_t n) { char* p = ws; ws += (n + 255) & ~(size_t)255; return p; };

  int*            gcur   = (int*)align256((size_t)K * 4);
  int*            src_b  = (int*)align256((size_t)K * cap * 4);
  unsigned short* ldst_b = (unsigned short*)align256((size_t)K * cap * 2);
  float*          dinv   = (float*)align256((size_t)N * 4);
  float*          xd     = (float*)align256((size_t)N * 4);
  float*          gd     = (float*)align256((size_t)N * 8);
  // shared region R: pdeg / pt1 / pt2 (sequentially dead -> alias)
  float*          R      = (float*)align256((size_t)SPLIT * 2 * Npad * 4);
  int*            pdeg   = (int*)R;
  float*          pt1    = R;
  float*          pt2    = R;

  float* out = (float*)d_out;

  int nb_node   = (N + TPB - 1) / TPB;
  int nb_bucket = (E + CHUNK - 1) / CHUNK;
  int nb_acc    = K * SPLIT;

  k_reset <<<(K + TPB - 1) / TPB, TPB, 0, stream>>>(gcur, K);
  k_bucket<<<nb_bucket, TPB, 0, stream>>>(src, dst, E, K, cap, gcur, src_b, ldst_b);
  k_deg   <<<nb_acc, TPB, 0, stream>>>(ldst_b, gcur, cap, pdeg, Npad);
  k_dinv  <<<nb_node, TPB, 0, stream>>>(pdeg, x, dinv, xd, N, Npad);
  k_pass1 <<<nb_acc, TPB, 0, stream>>>(src_b, ldst_b, gcur, cap, xd, pt1, Npad);
  k_node  <<<nb_node, TPB, 0, stream>>>(pt1, xd, dinv, W1, b1, W2, gd, N, Npad);
  k_pass2 <<<nb_acc, TPB, 0, stream>>>(src_b, ldst_b, gcur, cap, gd, pt2, Npad);
  k_final <<<nb_node, TPB, 0, stream>>>(pt2, gd, dinv, b2, out, N, Npad);
}

// Round 3
// 190.021 us; speedup vs baseline: 6.4756x; 1.4461x over previous
//
#include <hip/hip_runtime.h>

#define TPB 256
#define LOG_NPB 9
#define NPB 512            // nodes per bucket (bucket = dst >> 9)
#define SPLIT 4            // blocks per bucket in accumulation passes
#define CHUNK 8192         // edges per bucketing block
#define EPT 32             // edges per thread in bucketing (CHUNK/TPB)
#define KMAX 256           // max buckets (N=100000 -> K=196)

// GCN collapse (in-dim=1, out-dim=2):
//   deg[n] = 1 + #incoming; dinv = deg^-1/2; xd = x*dinv
//   t1[n] = sum_{e:dst=n} xd[src];  s = dinv*(t1+xd)
//   g[n][k] = sum_j relu(s*W1[j]+b1[j])*W2[j][k];  gd = g*dinv
//   t2[n][k] = sum_{e:dst=n} gd[src][k]
//   o = dinv*(t2+gd) + b2;  out = log_softmax(o)
// Edges packed to uint32 (src<<9 | dst&511), bucketed by dst via in-block
// LDS counting sort -> coalesced bucket writes, LDS-binned aggregation.

__global__ void k_reset(int* __restrict__ gcur, int K) {
  int i = blockIdx.x * blockDim.x + threadIdx.x;
  if (i < K) gcur[i] = 0;
}

__global__ __launch_bounds__(TPB) void
k_bucket(const int* __restrict__ src, const int* __restrict__ dst,
         int E, int K, int cap,
         int* __restrict__ gcur, unsigned int* __restrict__ packed) {
  __shared__ unsigned int stage[CHUNK];               // 32 KB
  __shared__ int hist[KMAX], start[KMAX], cur[KMAX], res[KMAX];
  __shared__ int sc[KMAX];

  const int t = threadIdx.x;
  const int e0 = blockIdx.x * CHUNK;
  const int e1 = min(e0 + CHUNK, E);

  for (int b = t; b < KMAX; b += TPB) hist[b] = 0;
  __syncthreads();

  unsigned int pk[EPT];
  unsigned int bb4[EPT / 4];
#pragma unroll
  for (int q = 0; q < EPT / 4; ++q) bb4[q] = 0xFFFFFFFFu;

  // phase 1: load (int4-coalesced), pack, histogram
#pragma unroll
  for (int q = 0; q < EPT / 4; ++q) {
    int base = e0 + 4 * t + q * 4 * TPB;
    if (base + 4 <= e1) {
      int4 dv = *reinterpret_cast<const int4*>(dst + base);
      int4 sv = *reinterpret_cast<const int4*>(src + base);
      int d[4] = {dv.x, dv.y, dv.z, dv.w};
      int s[4] = {sv.x, sv.y, sv.z, sv.w};
#pragma unroll
      for (int j = 0; j < 4; ++j) {
        int b = d[j] >> LOG_NPB;
        pk[4 * q + j] = ((unsigned)s[j] << LOG_NPB) | (unsigned)(d[j] & (NPB - 1));
        bb4[q] = (bb4[q] & ~(0xFFu << (8 * j))) | ((unsigned)b << (8 * j));
        atomicAdd(&hist[b], 1);
      }
    } else {
      for (int j = 0; j < 4; ++j) {
        int idx = base + j;
        if (idx < e1) {
          int d = dst[idx], s = src[idx];
          int b = d >> LOG_NPB;
          pk[4 * q + j] = ((unsigned)s << LOG_NPB) | (unsigned)(d & (NPB - 1));
          bb4[q] = (bb4[q] & ~(0xFFu << (8 * j))) | ((unsigned)b << (8 * j));
          atomicAdd(&hist[b], 1);
        }
      }
    }
  }
  __syncthreads();

  // phase 2: exclusive scan over KMAX bins (Hillis-Steele, TPB==KMAX)
  int hv = hist[t];
  sc[t] = hv;
  __syncthreads();
#pragma unroll
  for (int off = 1; off < KMAX; off <<= 1) {
    int u = (t >= off) ? sc[t - off] : 0;
    __syncthreads();
    sc[t] += u;
    __syncthreads();
  }
  start[t] = sc[t] - hv;
  cur[t] = sc[t] - hv;
  if (t < K && hv > 0) res[t] = atomicAdd(&gcur[t], hv);
  else res[t] = 0;
  __syncthreads();

  // phase 3: scatter into LDS sorted by bucket
#pragma unroll
  for (int k = 0; k < EPT; ++k) {
    int b = (bb4[k >> 2] >> (8 * (k & 3))) & 255;
    if (b != 255) {
      int p = atomicAdd(&cur[b], 1);
      stage[p] = pk[k];
    }
  }
  __syncthreads();

  // phase 4: coalesced copy-out, one wave per bucket round-robin
  int wid = t >> 6, lane = t & 63;
  for (int b = wid; b < K; b += TPB / 64) {
    int cnt = hist[b];
    int gbase = res[b];
    int lbase = start[b];
    for (int i = lane; i < cnt; i += 64) {
      int gp = gbase + i;
      if (gp < cap) packed[(size_t)b * cap + gp] = stage[lbase + i];
    }
  }
}

__device__ __forceinline__ void slice_range(int cnt, int s, int& off0, int& off1) {
  off0 = (int)(((long long)cnt * s) / SPLIT) & ~3;
  off1 = (s == SPLIT - 1) ? cnt : (int)(((long long)cnt * (s + 1)) / SPLIT) & ~3;
}

__global__ __launch_bounds__(TPB) void
k_deg(const unsigned int* __restrict__ packed, const int* __restrict__ gcur,
      int cap, int* __restrict__ pdeg, int Npad) {
  int b = blockIdx.x / SPLIT, s = blockIdx.x % SPLIT;
  __shared__ int bins[NPB];
  for (int i = threadIdx.x; i < NPB; i += TPB) bins[i] = 0;
  __syncthreads();
  int cnt = min(gcur[b], cap);
  int off0, off1; slice_range(cnt, s, off0, off1);
  const unsigned int* base = packed + (size_t)b * cap;
  for (int e = off0 + 4 * threadIdx.x; e < off1; e += 4 * TPB) {
    if (e + 4 <= off1) {
      uint4 p = *reinterpret_cast<const uint4*>(base + e);
      atomicAdd(&bins[p.x & (NPB - 1)], 1);
      atomicAdd(&bins[p.y & (NPB - 1)], 1);
      atomicAdd(&bins[p.z & (NPB - 1)], 1);
      atomicAdd(&bins[p.w & (NPB - 1)], 1);
    } else {
      for (int j = e; j < off1; ++j) atomicAdd(&bins[base[j] & (NPB - 1)], 1);
    }
  }
  __syncthreads();
  int nb = b << LOG_NPB;
  for (int i = threadIdx.x; i < NPB; i += TPB)
    pdeg[s * Npad + nb + i] = bins[i];
}

__global__ void k_dinv(const int* __restrict__ pdeg, const float* __restrict__ x,
                       float* __restrict__ dinv, float* __restrict__ xd,
                       int N, int Npad) {
  int i = blockIdx.x * TPB + threadIdx.x;
  if (i >= N) return;
  int d = 1;  // self-loop
#pragma unroll
  for (int s = 0; s < SPLIT; ++s) d += pdeg[s * Npad + i];
  float di = rsqrtf((float)d);
  dinv[i] = di;
  xd[i] = x[i] * di;
}

__global__ __launch_bounds__(TPB) void
k_pass1(const unsigned int* __restrict__ packed, const int* __restrict__ gcur,
        int cap, const float* __restrict__ xd, float* __restrict__ pt1, int Npad) {
  int b = blockIdx.x / SPLIT, s = blockIdx.x % SPLIT;
  __shared__ float bins[NPB];
  for (int i = threadIdx.x; i < NPB; i += TPB) bins[i] = 0.f;
  __syncthreads();
  int cnt = min(gcur[b], cap);
  int off0, off1; slice_range(cnt, s, off0, off1);
  const unsigned int* base = packed + (size_t)b * cap;
  for (int e = off0 + 4 * threadIdx.x; e < off1; e += 4 * TPB) {
    if (e + 4 <= off1) {
      uint4 p = *reinterpret_cast<const uint4*>(base + e);
      atomicAdd(&bins[p.x & (NPB - 1)], xd[p.x >> LOG_NPB]);
      atomicAdd(&bins[p.y & (NPB - 1)], xd[p.y >> LOG_NPB]);
      atomicAdd(&bins[p.z & (NPB - 1)], xd[p.z >> LOG_NPB]);
      atomicAdd(&bins[p.w & (NPB - 1)], xd[p.w >> LOG_NPB]);
    } else {
      for (int j = e; j < off1; ++j)
        atomicAdd(&bins[base[j] & (NPB - 1)], xd[base[j] >> LOG_NPB]);
    }
  }
  __syncthreads();
  int nb = b << LOG_NPB;
  for (int i = threadIdx.x; i < NPB; i += TPB)
    pt1[s * Npad + nb + i] = bins[i];
}

__global__ void k_node(const float* __restrict__ pt1, const float* __restrict__ xd,
                       const float* __restrict__ dinv,
                       const float* __restrict__ W1, const float* __restrict__ b1,
                       const float* __restrict__ W2,
                       float* __restrict__ gd, int N, int Npad) {
  int i = blockIdx.x * TPB + threadIdx.x;
  if (i >= N) return;
  float tv = 0.f;
#pragma unroll
  for (int s = 0; s < SPLIT; ++s) tv += pt1[s * Npad + i];
  float di = dinv[i];
  float sv = di * (tv + xd[i]);
  float g0 = 0.f, g1 = 0.f;
#pragma unroll
  for (int j = 0; j < 16; ++j) {
    float h = fmaxf(fmaf(sv, W1[j], b1[j]), 0.f);
    g0 = fmaf(h, W2[2 * j], g0);
    g1 = fmaf(h, W2[2 * j + 1], g1);
  }
  float2 o;
  o.x = g0 * di;
  o.y = g1 * di;
  *reinterpret_cast<float2*>(gd + 2 * i) = o;
}

__global__ __launch_bounds__(TPB) void
k_pass2(const unsigned int* __restrict__ packed, const int* __restrict__ gcur,
        int cap, const float* __restrict__ gd, float* __restrict__ pt2, int Npad) {
  int b = blockIdx.x / SPLIT, s = blockIdx.x % SPLIT;
  __shared__ float binx[NPB];
  __shared__ float biny[NPB];
  for (int i = threadIdx.x; i < NPB; i += TPB) { binx[i] = 0.f; biny[i] = 0.f; }
  __syncthreads();
  int cnt = min(gcur[b], cap);
  int off0, off1; slice_range(cnt, s, off0, off1);
  const unsigned int* base = packed + (size_t)b * cap;
  for (int e = off0 + 4 * threadIdx.x; e < off1; e += 4 * TPB) {
    if (e + 4 <= off1) {
      uint4 p = *reinterpret_cast<const uint4*>(base + e);
      float2 g0 = *reinterpret_cast<const float2*>(gd + 2 * (size_t)(p.x >> LOG_NPB));
      float2 g1 = *reinterpret_cast<const float2*>(gd + 2 * (size_t)(p.y >> LOG_NPB));
      float2 g2 = *reinterpret_cast<const float2*>(gd + 2 * (size_t)(p.z >> LOG_NPB));
      float2 g3 = *reinterpret_cast<const float2*>(gd + 2 * (size_t)(p.w >> LOG_NPB));
      atomicAdd(&binx[p.x & (NPB - 1)], g0.x);
      atomicAdd(&biny[p.x & (NPB - 1)], g0.y);
      atomicAdd(&binx[p.y & (NPB - 1)], g1.x);
      atomicAdd(&biny[p.y & (NPB - 1)], g1.y);
      atomicAdd(&binx[p.z & (NPB - 1)], g2.x);
      atomicAdd(&biny[p.z & (NPB - 1)], g2.y);
      atomicAdd(&binx[p.w & (NPB - 1)], g3.x);
      atomicAdd(&biny[p.w & (NPB - 1)], g3.y);
    } else {
      for (int j = e; j < off1; ++j) {
        unsigned int p = base[j];
        float2 g = *reinterpret_cast<const float2*>(gd + 2 * (size_t)(p >> LOG_NPB));
        atomicAdd(&binx[p & (NPB - 1)], g.x);
        atomicAdd(&biny[p & (NPB - 1)], g.y);
      }
    }
  }
  __syncthreads();
  int nb = b << LOG_NPB;
  for (int i = threadIdx.x; i < NPB; i += TPB) {
    float2 o;
    o.x = binx[i];
    o.y = biny[i];
    *reinterpret_cast<float2*>(pt2 + (size_t)s * 2 * Npad + 2 * (nb + i)) = o;
  }
}

__global__ void k_final(const float* __restrict__ pt2, const float* __restrict__ gd,
                        const float* __restrict__ dinv, const float* __restrict__ b2,
                        float* __restrict__ out, int N, int Npad) {
  int i = blockIdx.x * TPB + threadIdx.x;
  if (i >= N) return;
  float t0 = 0.f, t1 = 0.f;
#pragma unroll
  for (int s = 0; s < SPLIT; ++s) {
    float2 p = *reinterpret_cast<const float2*>(pt2 + (size_t)s * 2 * Npad + 2 * i);
    t0 += p.x;
    t1 += p.y;
  }
  float di = dinv[i];
  float o0 = di * (t0 + gd[2 * i]) + b2[0];
  float o1 = di * (t1 + gd[2 * i + 1]) + b2[1];
  float m = fmaxf(o0, o1);
  float l = m + logf(expf(o0 - m) + expf(o1 - m));
  out[2 * i] = o0 - l;
  out[2 * i + 1] = o1 - l;
}

extern "C" void kernel_launch(void* const* d_in, const int* in_sizes, int n_in,
                              void* d_out, int out_size, void* d_ws, size_t ws_size,
                              hipStream_t stream) {
  const float* x  = (const float*)d_in[0];
  const int*   ei = (const int*)d_in[1];
  const float* W1 = (const float*)d_in[2];
  const float* b1 = (const float*)d_in[3];
  const float* W2 = (const float*)d_in[4];
  const float* b2 = (const float*)d_in[5];

  const int N = in_sizes[0];      // x is [N,1]
  const int E = in_sizes[1] / 2;  // edge_index is [2,E]
  const int* src = ei;
  const int* dst = ei + E;

  const int K = (N + NPB - 1) >> LOG_NPB;   // 196
  const int Npad = K << LOG_NPB;            // 100352
  int mean = (int)(((long long)E * NPB) / N);
  int cap = mean + mean / 16 + 512;         // slack >> binomial std
  cap = (cap + 3) & ~3;

  char* ws = (char*)d_ws;
  auto align256 = [&](size_t n) { char* p = ws; ws += (n + 255) & ~(size_t)255; return p; };

  int*          gcur   = (int*)align256((size_t)K * 4);
  unsigned int* packed = (unsigned int*)align256((size_t)K * cap * 4);
  float*        dinv   = (float*)align256((size_t)N * 4);
  float*        xd     = (float*)align256((size_t)N * 4);
  float*        gd     = (float*)align256((size_t)N * 8);
  // shared region R: pdeg / pt1 / pt2 (sequentially dead -> alias)
  float*        R      = (float*)align256((size_t)SPLIT * 2 * Npad * 4);
  int*          pdeg   = (int*)R;
  float*        pt1    = R;
  float*        pt2    = R;

  float* out = (float*)d_out;

  int nb_node   = (N + TPB - 1) / TPB;
  int nb_bucket = (E + CHUNK - 1) / CHUNK;
  int nb_acc    = K * SPLIT;

  k_reset <<<(K + TPB - 1) / TPB, TPB, 0, stream>>>(gcur, K);
  k_bucket<<<nb_bucket, TPB, 0, stream>>>(src, dst, E, K, cap, gcur, packed);
  k_deg   <<<nb_acc, TPB, 0, stream>>>(packed, gcur, cap, pdeg, Npad);
  k_dinv  <<<nb_node, TPB, 0, stream>>>(pdeg, x, dinv, xd, N, Npad);
  k_pass1 <<<nb_acc, TPB, 0, stream>>>(packed, gcur, cap, xd, pt1, Npad);
  k_node  <<<nb_node, TPB, 0, stream>>>(pt1, xd, dinv, W1, b1, W2, gd, N, Npad);
  k_pass2 <<<nb_acc, TPB, 0, stream>>>(packed, gcur, cap, gd, pt2, Npad);
  k_final <<<nb_node, TPB, 0, stream>>>(pt2, gd, dinv, b2, out, N, Npad);
}

// Round 4
// 184.957 us; speedup vs baseline: 6.6529x; 1.0274x over previous
//
#include <hip/hip_runtime.h>

#define TPB 256
#define LOG_NPB 9
#define NPB 512            // nodes per bucket (bucket = dst >> 9)
#define SPLIT 16           // blocks per bucket in accumulation passes
#define CHUNK 4096         // edges per bucketing block
#define EPT 16             // edges per thread in bucketing (CHUNK/TPB)
#define KMAX 256           // max buckets (N=100000 -> K=196)

// GCN collapse (in-dim=1, out-dim=2):
//   deg[n] = 1 + #incoming; dinv = deg^-1/2; xd = x*dinv
//   t1[n] = sum_{e:dst=n} xd[src];  s = dinv*(t1+xd)
//   g[n][k] = sum_j relu(s*W1[j]+b1[j])*W2[j][k];  gd = g*dinv
//   t2[n][k] = sum_{e:dst=n} gd[src][k]
//   o = dinv*(t2+gd) + b2;  out = log_softmax(o)
// Edges packed to uint32 (src<<9 | dst&511), bucketed by dst via in-block
// LDS counting sort -> coalesced bucket writes, LDS-binned aggregation.

__global__ void k_reset(int* __restrict__ gcur, int K) {
  int i = blockIdx.x * blockDim.x + threadIdx.x;
  if (i < K) gcur[i] = 0;
}

__global__ __launch_bounds__(TPB) void
k_bucket(const int* __restrict__ src, const int* __restrict__ dst,
         int E, int K, int cap,
         int* __restrict__ gcur, unsigned int* __restrict__ packed) {
  __shared__ unsigned int stage[CHUNK];               // 16 KB
  __shared__ unsigned char bkt[CHUNK];                // 4 KB
  __shared__ int hist[KMAX], start[KMAX], cur[KMAX], res[KMAX];
  __shared__ int sc[KMAX];

  const int t = threadIdx.x;
  const int e0 = blockIdx.x * CHUNK;
  const int e1 = min(e0 + CHUNK, E);
  const int cn = e1 - e0;

  for (int b = t; b < KMAX; b += TPB) hist[b] = 0;
  __syncthreads();

  unsigned int pk[EPT];
  unsigned int bb4[EPT / 4];
#pragma unroll
  for (int q = 0; q < EPT / 4; ++q) bb4[q] = 0xFFFFFFFFu;

  // phase 1: load (int4-coalesced), pack, histogram
#pragma unroll
  for (int q = 0; q < EPT / 4; ++q) {
    int base = e0 + 4 * t + q * 4 * TPB;
    if (base + 4 <= e1) {
      int4 dv = *reinterpret_cast<const int4*>(dst + base);
      int4 sv = *reinterpret_cast<const int4*>(src + base);
      int d[4] = {dv.x, dv.y, dv.z, dv.w};
      int s[4] = {sv.x, sv.y, sv.z, sv.w};
#pragma unroll
      for (int j = 0; j < 4; ++j) {
        int b = d[j] >> LOG_NPB;
        pk[4 * q + j] = ((unsigned)s[j] << LOG_NPB) | (unsigned)(d[j] & (NPB - 1));
        bb4[q] = (bb4[q] & ~(0xFFu << (8 * j))) | ((unsigned)b << (8 * j));
        atomicAdd(&hist[b], 1);
      }
    } else {
      for (int j = 0; j < 4; ++j) {
        int idx = base + j;
        if (idx < e1) {
          int d = dst[idx], s = src[idx];
          int b = d >> LOG_NPB;
          pk[4 * q + j] = ((unsigned)s << LOG_NPB) | (unsigned)(d & (NPB - 1));
          bb4[q] = (bb4[q] & ~(0xFFu << (8 * j))) | ((unsigned)b << (8 * j));
          atomicAdd(&hist[b], 1);
        }
      }
    }
  }
  __syncthreads();

  // phase 2: exclusive scan over KMAX bins (Hillis-Steele, TPB==KMAX)
  int hv = hist[t];
  sc[t] = hv;
  __syncthreads();
#pragma unroll
  for (int off = 1; off < KMAX; off <<= 1) {
    int u = (t >= off) ? sc[t - off] : 0;
    __syncthreads();
    sc[t] += u;
    __syncthreads();
  }
  start[t] = sc[t] - hv;
  cur[t] = sc[t] - hv;
  res[t] = (t < K && hv > 0) ? atomicAdd(&gcur[t], hv) : 0;
  __syncthreads();

  // phase 3: scatter into LDS sorted by bucket, remember bucket per slot
#pragma unroll
  for (int k = 0; k < EPT; ++k) {
    int b = (bb4[k >> 2] >> (8 * (k & 3))) & 255;
    if (b != 255) {
      int p = atomicAdd(&cur[b], 1);
      stage[p] = pk[k];
      bkt[p] = (unsigned char)b;
    }
  }
  __syncthreads();

  // phase 4: linear copy-out — all threads active, coalesced per-bucket runs
  for (int i = t; i < cn; i += TPB) {
    int b = bkt[i];
    int gp = res[b] + i - start[b];
    if (gp < cap) packed[(size_t)b * cap + gp] = stage[i];
  }
}

__device__ __forceinline__ void slice_range(int cnt, int s, int& off0, int& off1) {
  off0 = (int)(((long long)cnt * s) / SPLIT) & ~3;
  off1 = (s == SPLIT - 1) ? cnt : (int)(((long long)cnt * (s + 1)) / SPLIT) & ~3;
}

__global__ __launch_bounds__(TPB) void
k_deg(const unsigned int* __restrict__ packed, const int* __restrict__ gcur,
      int cap, int* __restrict__ pdeg, int Npad) {
  int b = blockIdx.x / SPLIT, s = blockIdx.x % SPLIT;
  __shared__ int bins[NPB];
  for (int i = threadIdx.x; i < NPB; i += TPB) bins[i] = 0;
  __syncthreads();
  int cnt = min(gcur[b], cap);
  int off0, off1; slice_range(cnt, s, off0, off1);
  const unsigned int* base = packed + (size_t)b * cap;
  for (int e = off0 + 4 * threadIdx.x; e < off1; e += 4 * TPB) {
    if (e + 4 <= off1) {
      uint4 p = *reinterpret_cast<const uint4*>(base + e);
      atomicAdd(&bins[p.x & (NPB - 1)], 1);
      atomicAdd(&bins[p.y & (NPB - 1)], 1);
      atomicAdd(&bins[p.z & (NPB - 1)], 1);
      atomicAdd(&bins[p.w & (NPB - 1)], 1);
    } else {
      for (int j = e; j < off1; ++j) atomicAdd(&bins[base[j] & (NPB - 1)], 1);
    }
  }
  __syncthreads();
  int nb = b << LOG_NPB;
  for (int i = threadIdx.x; i < NPB; i += TPB)
    pdeg[s * Npad + nb + i] = bins[i];
}

__global__ void k_dinv(const int* __restrict__ pdeg, const float* __restrict__ x,
                       float* __restrict__ dinv, float* __restrict__ xd,
                       int N, int Npad) {
  int i = blockIdx.x * TPB + threadIdx.x;
  if (i >= N) return;
  int d = 1;  // self-loop
#pragma unroll
  for (int s = 0; s < SPLIT; ++s) d += pdeg[s * Npad + i];
  float di = rsqrtf((float)d);
  dinv[i] = di;
  xd[i] = x[i] * di;
}

__global__ __launch_bounds__(TPB) void
k_pass1(const unsigned int* __restrict__ packed, const int* __restrict__ gcur,
        int cap, const float* __restrict__ xd, float* __restrict__ pt1, int Npad) {
  int b = blockIdx.x / SPLIT, s = blockIdx.x % SPLIT;
  __shared__ float bins[NPB];
  for (int i = threadIdx.x; i < NPB; i += TPB) bins[i] = 0.f;
  __syncthreads();
  int cnt = min(gcur[b], cap);
  int off0, off1; slice_range(cnt, s, off0, off1);
  const unsigned int* base = packed + (size_t)b * cap;
  for (int e = off0 + 4 * threadIdx.x; e < off1; e += 4 * TPB) {
    if (e + 4 <= off1) {
      uint4 p = *reinterpret_cast<const uint4*>(base + e);
      float vx = xd[p.x >> LOG_NPB];
      float vy = xd[p.y >> LOG_NPB];
      float vz = xd[p.z >> LOG_NPB];
      float vw = xd[p.w >> LOG_NPB];
      atomicAdd(&bins[p.x & (NPB - 1)], vx);
      atomicAdd(&bins[p.y & (NPB - 1)], vy);
      atomicAdd(&bins[p.z & (NPB - 1)], vz);
      atomicAdd(&bins[p.w & (NPB - 1)], vw);
    } else {
      for (int j = e; j < off1; ++j)
        atomicAdd(&bins[base[j] & (NPB - 1)], xd[base[j] >> LOG_NPB]);
    }
  }
  __syncthreads();
  int nb = b << LOG_NPB;
  for (int i = threadIdx.x; i < NPB; i += TPB)
    pt1[s * Npad + nb + i] = bins[i];
}

__global__ void k_node(const float* __restrict__ pt1, const float* __restrict__ xd,
                       const float* __restrict__ dinv,
                       const float* __restrict__ W1, const float* __restrict__ b1,
                       const float* __restrict__ W2,
                       float* __restrict__ gd, int N, int Npad) {
  int i = blockIdx.x * TPB + threadIdx.x;
  if (i >= N) return;
  float tv = 0.f;
#pragma unroll
  for (int s = 0; s < SPLIT; ++s) tv += pt1[s * Npad + i];
  float di = dinv[i];
  float sv = di * (tv + xd[i]);
  float g0 = 0.f, g1 = 0.f;
#pragma unroll
  for (int j = 0; j < 16; ++j) {
    float h = fmaxf(fmaf(sv, W1[j], b1[j]), 0.f);
    g0 = fmaf(h, W2[2 * j], g0);
    g1 = fmaf(h, W2[2 * j + 1], g1);
  }
  float2 o;
  o.x = g0 * di;
  o.y = g1 * di;
  *reinterpret_cast<float2*>(gd + 2 * i) = o;
}

__global__ __launch_bounds__(TPB) void
k_pass2(const unsigned int* __restrict__ packed, const int* __restrict__ gcur,
        int cap, const float* __restrict__ gd, float* __restrict__ pt2, int Npad) {
  int b = blockIdx.x / SPLIT, s = blockIdx.x % SPLIT;
  __shared__ float binx[NPB];
  __shared__ float biny[NPB];
  for (int i = threadIdx.x; i < NPB; i += TPB) { binx[i] = 0.f; biny[i] = 0.f; }
  __syncthreads();
  int cnt = min(gcur[b], cap);
  int off0, off1; slice_range(cnt, s, off0, off1);
  const unsigned int* base = packed + (size_t)b * cap;
  for (int e = off0 + 4 * threadIdx.x; e < off1; e += 4 * TPB) {
    if (e + 4 <= off1) {
      uint4 p = *reinterpret_cast<const uint4*>(base + e);
      float2 g0 = *reinterpret_cast<const float2*>(gd + 2 * (size_t)(p.x >> LOG_NPB));
      float2 g1 = *reinterpret_cast<const float2*>(gd + 2 * (size_t)(p.y >> LOG_NPB));
      float2 g2 = *reinterpret_cast<const float2*>(gd + 2 * (size_t)(p.z >> LOG_NPB));
      float2 g3 = *reinterpret_cast<const float2*>(gd + 2 * (size_t)(p.w >> LOG_NPB));
      atomicAdd(&binx[p.x & (NPB - 1)], g0.x);
      atomicAdd(&biny[p.x & (NPB - 1)], g0.y);
      atomicAdd(&binx[p.y & (NPB - 1)], g1.x);
      atomicAdd(&biny[p.y & (NPB - 1)], g1.y);
      atomicAdd(&binx[p.z & (NPB - 1)], g2.x);
      atomicAdd(&biny[p.z & (NPB - 1)], g2.y);
      atomicAdd(&binx[p.w & (NPB - 1)], g3.x);
      atomicAdd(&biny[p.w & (NPB - 1)], g3.y);
    } else {
      for (int j = e; j < off1; ++j) {
        unsigned int p = base[j];
        float2 g = *reinterpret_cast<const float2*>(gd + 2 * (size_t)(p >> LOG_NPB));
        atomicAdd(&binx[p & (NPB - 1)], g.x);
        atomicAdd(&biny[p & (NPB - 1)], g.y);
      }
    }
  }
  __syncthreads();
  int nb = b << LOG_NPB;
  for (int i = threadIdx.x; i < NPB; i += TPB) {
    float2 o;
    o.x = binx[i];
    o.y = biny[i];
    *reinterpret_cast<float2*>(pt2 + (size_t)s * 2 * Npad + 2 * (nb + i)) = o;
  }
}

__global__ void k_final(const float* __restrict__ pt2, const float* __restrict__ gd,
                        const float* __restrict__ dinv, const float* __restrict__ b2,
                        float* __restrict__ out, int N, int Npad) {
  int i = blockIdx.x * TPB + threadIdx.x;
  if (i >= N) return;
  float t0 = 0.f, t1 = 0.f;
#pragma unroll
  for (int s = 0; s < SPLIT; ++s) {
    float2 p = *reinterpret_cast<const float2*>(pt2 + (size_t)s * 2 * Npad + 2 * i);
    t0 += p.x;
    t1 += p.y;
  }
  float di = dinv[i];
  float o0 = di * (t0 + gd[2 * i]) + b2[0];
  float o1 = di * (t1 + gd[2 * i + 1]) + b2[1];
  float m = fmaxf(o0, o1);
  float l = m + logf(expf(o0 - m) + expf(o1 - m));
  out[2 * i] = o0 - l;
  out[2 * i + 1] = o1 - l;
}

extern "C" void kernel_launch(void* const* d_in, const int* in_sizes, int n_in,
                              void* d_out, int out_size, void* d_ws, size_t ws_size,
                              hipStream_t stream) {
  const float* x  = (const float*)d_in[0];
  const int*   ei = (const int*)d_in[1];
  const float* W1 = (const float*)d_in[2];
  const float* b1 = (const float*)d_in[3];
  const float* W2 = (const float*)d_in[4];
  const float* b2 = (const float*)d_in[5];

  const int N = in_sizes[0];      // x is [N,1]
  const int E = in_sizes[1] / 2;  // edge_index is [2,E]
  const int* src = ei;
  const int* dst = ei + E;

  const int K = (N + NPB - 1) >> LOG_NPB;   // 196
  const int Npad = K << LOG_NPB;            // 100352
  int mean = (int)(((long long)E * NPB) / N);
  int cap = mean + mean / 16 + 512;         // slack >> binomial std
  cap = (cap + 3) & ~3;

  char* ws = (char*)d_ws;
  auto align256 = [&](size_t n) { char* p = ws; ws += (n + 255) & ~(size_t)255; return p; };

  int*          gcur   = (int*)align256((size_t)K * 4);
  unsigned int* packed = (unsigned int*)align256((size_t)K * cap * 4);
  float*        dinv   = (float*)align256((size_t)N * 4);
  float*        xd     = (float*)align256((size_t)N * 4);
  float*        gd     = (float*)align256((size_t)N * 8);
  // shared region R: pdeg / pt1 / pt2 (sequentially dead -> alias)
  float*        R      = (float*)align256((size_t)SPLIT * 2 * Npad * 4);
  int*          pdeg   = (int*)R;
  float*        pt1    = R;
  float*        pt2    = R;

  float* out = (float*)d_out;

  int nb_node   = (N + TPB - 1) / TPB;
  int nb_bucket = (E + CHUNK - 1) / CHUNK;
  int nb_acc    = K * SPLIT;

  k_reset <<<(K + TPB - 1) / TPB, TPB, 0, stream>>>(gcur, K);
  k_bucket<<<nb_bucket, TPB, 0, stream>>>(src, dst, E, K, cap, gcur, packed);
  k_deg   <<<nb_acc, TPB, 0, stream>>>(packed, gcur, cap, pdeg, Npad);
  k_dinv  <<<nb_node, TPB, 0, stream>>>(pdeg, x, dinv, xd, N, Npad);
  k_pass1 <<<nb_acc, TPB, 0, stream>>>(packed, gcur, cap, xd, pt1, Npad);
  k_node  <<<nb_node, TPB, 0, stream>>>(pt1, xd, dinv, W1, b1, W2, gd, N, Npad);
  k_pass2 <<<nb_acc, TPB, 0, stream>>>(packed, gcur, cap, gd, pt2, Npad);
  k_final <<<nb_node, TPB, 0, stream>>>(pt2, gd, dinv, b2, out, N, Npad);
}